// Round 1
// baseline (1775.734 us; speedup 1.0000x reference)
//
#include <hip/hip_runtime.h>
#include <math.h>

constexpr int GG  = 1024;   // graphs
constexpr int NN  = 256;    // nodes layer0
constexpr int FF  = 128;    // input feat
constexpr int DD  = 256;    // hidden
constexpr int KS0 = 32, KS1 = 16, KS2 = 8;
constexpr int MAXNB = 96;   // max neighbors stored (deg ~ Binom(255,0.121), max ~55)

__device__ __forceinline__ float lrelu(float x){ return x >= 0.f ? x : 0.01f*x; }

// ---------------- CSR build + norm (layer 0) ----------------
__global__ void k_csr(const float* __restrict__ adj, float* __restrict__ norm0,
                      int* __restrict__ cnt0, unsigned char* __restrict__ nbr0) {
  int g = blockIdx.x;
  int lane = threadIdx.x & 63;
  int wave = threadIdx.x >> 6;
  const float* A = adj + (size_t)g*NN*NN;
  for (int r = wave*64; r < wave*64 + 64; ++r) {
    unsigned char* nb = nbr0 + ((size_t)g*NN + r)*MAXNB;
    int cnt = 0;
    for (int ch = 0; ch < 4; ++ch) {
      float v = A[(size_t)r*NN + ch*64 + lane];
      unsigned long long mask = __ballot(v > 0.5f);
      int pos = __popcll(mask & ((1ull << lane) - 1ull));
      if (v > 0.5f && cnt + pos < MAXNB) nb[cnt + pos] = (unsigned char)(ch*64 + lane);
      cnt += __popcll(mask);
    }
    if (lane == 0) {
      cnt0[g*NN + r] = cnt < MAXNB ? cnt : MAXNB;
      norm0[g*NN + r] = rsqrtf(fmaxf((float)cnt, 1.0f));
    }
  }
}

// ---------------- sparse A @ (X*norm), layer 0, col-half passes ----------------
__global__ void k_spmm0(const float* __restrict__ feat, const float* __restrict__ norm0,
                        const int* __restrict__ cnt0, const unsigned char* __restrict__ nbr0,
                        float* __restrict__ T0) {
  __shared__ float lx[NN*64];                 // 64KB: all rows x 64 cols
  int g = blockIdx.x;
  int t = threadIdx.x;
  int lane = t & 63, wave = t >> 6;
  const float* X = feat + (size_t)g*NN*FF;
  for (int p = 0; p < 2; ++p) {
    __syncthreads();
    for (int i = 0; i < 64; ++i) {
      int idx = t + i*256;                    // 0..16383
      int m = idx >> 6, c = idx & 63;
      lx[idx] = X[m*FF + p*64 + c] * norm0[g*NN + m];
    }
    __syncthreads();
    for (int r = wave*64; r < wave*64 + 64; ++r) {
      int cnt = cnt0[g*NN + r];
      const unsigned char* nb = nbr0 + ((size_t)g*NN + r)*MAXNB;
      float acc = 0.f;
      for (int j = 0; j < cnt; ++j) {
        int m = nb[j];
        acc += lx[m*64 + lane];
      }
      T0[((size_t)g*NN + r)*FF + p*64 + lane] = acc;
    }
  }
}

// ---------------- dense GEMM: out = lrelu(norm[row]*(T@W) + bias), N=256 ----------------
template<int K>
__global__ __launch_bounds__(256) void k_gemm(const float* __restrict__ Tmat,
                       const float* __restrict__ W,
                       const float* __restrict__ normv, const float* __restrict__ bias,
                       float* __restrict__ out) {
  __shared__ float As[128*65];
  __shared__ float Bs[64*64];
  int m0 = blockIdx.x * 128;
  int n0 = blockIdx.y * 64;
  int t = threadIdx.x;
  int tx = t & 15, ty = t >> 4;
  float acc[8][4] = {};
  for (int kt = 0; kt < K; kt += 64) {
    __syncthreads();
    #pragma unroll
    for (int i = 0; i < 32; ++i) {
      int idx = t + i*256;                    // 128x64
      int r = idx >> 6, k = idx & 63;
      As[r*65 + k] = Tmat[(size_t)(m0 + r)*K + kt + k];
    }
    #pragma unroll
    for (int i = 0; i < 16; ++i) {
      int idx = t + i*256;                    // 64x64
      int k = idx >> 6, n = idx & 63;
      Bs[k*64 + n] = W[(size_t)(kt + k)*DD + n0 + n];
    }
    __syncthreads();
    for (int k = 0; k < 64; ++k) {
      float a[8];
      #pragma unroll
      for (int i = 0; i < 8; ++i) a[i] = As[(ty*8 + i)*65 + k];
      float4 b = *reinterpret_cast<const float4*>(&Bs[k*64 + tx*4]);
      #pragma unroll
      for (int i = 0; i < 8; ++i) {
        acc[i][0] += a[i]*b.x; acc[i][1] += a[i]*b.y;
        acc[i][2] += a[i]*b.z; acc[i][3] += a[i]*b.w;
      }
    }
  }
  #pragma unroll
  for (int i = 0; i < 8; ++i) {
    int row = m0 + ty*8 + i;
    float nv = normv[row];
    #pragma unroll
    for (int j = 0; j < 4; ++j) {
      int col = n0 + tx*4 + j;
      out[(size_t)row*DD + col] = lrelu(nv*acc[i][j] + bias[col]);
    }
  }
}

// ---------------- hs[row] = norm[row] * dot(X[row,:256], Ws) ----------------
__global__ void k_hs(const float* __restrict__ X, const float* __restrict__ Ws,
                     const float* __restrict__ normv, float* __restrict__ hs) {
  int row = blockIdx.x*4 + (threadIdx.x >> 6);
  int lane = threadIdx.x & 63;
  const float* x = X + (size_t)row*DD;
  float s = x[lane]*Ws[lane] + x[lane+64]*Ws[lane+64]
          + x[lane+128]*Ws[lane+128] + x[lane+192]*Ws[lane+192];
  for (int off = 32; off; off >>= 1) s += __shfl_xor(s, off);
  if (lane == 0) hs[row] = normv[row]*s;
}

// ---------------- score layer0 (sparse) ----------------
__global__ void k_score0(const float* __restrict__ hs, const int* __restrict__ cnt0,
                         const unsigned char* __restrict__ nbr0, const float* __restrict__ norm0,
                         const float* __restrict__ bs, float* __restrict__ score) {
  int g = blockIdx.x; int r = threadIdx.x;
  int cnt = cnt0[g*NN + r];
  const unsigned char* nb = nbr0 + ((size_t)g*NN + r)*MAXNB;
  float s = 0.f;
  for (int j = 0; j < cnt; ++j) s += hs[g*NN + nb[j]];
  score[g*NN + r] = norm0[g*NN + r]*s + bs[0];
}

// ---------------- score layers 1/2 (dense small) ----------------
template<int n>
__global__ void k_score_dense(const float* __restrict__ a, const float* __restrict__ hs,
                              const float* __restrict__ normv, const float* __restrict__ bs,
                              float* __restrict__ score) {
  int row = blockIdx.x*blockDim.x + threadIdx.x;   // over GG*n
  if (row >= GG*n) return;
  int g = row / n;
  const float* ar = a + (size_t)g*n*n + (size_t)(row - g*n)*n;
  float s = 0.f;
  for (int m = 0; m < n; ++m) s += ar[m]*hs[g*n + m];
  score[row] = normv[row]*s + bs[0];
}

// ---------------- top-k per graph (one wave per graph), ties -> lower index ----------------
template<int n, int k>
__global__ void k_topk(const float* __restrict__ score, int* __restrict__ idx_out,
                       float* __restrict__ tv_out) {
  int g = blockIdx.x*4 + (threadIdx.x >> 6);
  int lane = threadIdx.x & 63;
  constexpr int E = (n + 63)/64;
  float s[E]; int si[E];
  #pragma unroll
  for (int e = 0; e < E; ++e) {
    int i = e*64 + lane;
    if (i < n) { s[e] = score[(size_t)g*n + i]; si[e] = i; }
    else { s[e] = -INFINITY; si[e] = 1 << 30; }
  }
  for (int kk = 0; kk < k; ++kk) {
    float bs_ = -INFINITY; int bi = 1 << 30;
    #pragma unroll
    for (int e = 0; e < E; ++e)
      if (s[e] > bs_ || (s[e] == bs_ && si[e] < bi)) { bs_ = s[e]; bi = si[e]; }
    for (int off = 32; off; off >>= 1) {
      float os = __shfl_xor(bs_, off);
      int oi = __shfl_xor(bi, off);
      if (os > bs_ || (os == bs_ && oi < bi)) { bs_ = os; bi = oi; }
    }
    if (lane == 0) { idx_out[(size_t)g*k + kk] = bi; tv_out[(size_t)g*k + kk] = tanhf(bs_); }
    #pragma unroll
    for (int e = 0; e < E; ++e) if (si[e] == bi) s[e] = -INFINITY;
  }
}

// ---------------- gathers + readouts ----------------
__global__ void k_gather0(const float* __restrict__ x1, const float* __restrict__ adj,
                          const int* __restrict__ idx, const float* __restrict__ tv,
                          float* __restrict__ x_sel, float* __restrict__ a1,
                          float* __restrict__ merged) {
  __shared__ int sidx[KS0]; __shared__ float stv[KS0];
  int g = blockIdx.x; int t = threadIdx.x;
  if (t < KS0) { sidx[t] = idx[g*KS0 + t]; stv[t] = tv[g*KS0 + t]; }
  __syncthreads();
  float sum = 0.f, mx = -INFINITY;
  for (int j = 0; j < KS0; ++j) {
    float v = x1[((size_t)g*NN + sidx[j])*DD + t] * stv[j];
    x_sel[((size_t)g*KS0 + j)*DD + t] = v;
    sum += v; mx = fmaxf(mx, v);
  }
  merged[(size_t)g*1536 + t] = sum;
  merged[(size_t)g*1536 + 256 + t] = mx;
  for (int e = t; e < KS0*KS0; e += 256) {
    int r = e >> 5, c = e & 31;
    a1[(size_t)g*KS0*KS0 + e] = adj[(size_t)g*NN*NN + (size_t)sidx[r]*NN + sidx[c]];
  }
}

__global__ void k_gather1(const float* __restrict__ x2, const float* __restrict__ a1,
                          const int* __restrict__ idx, const float* __restrict__ tv,
                          float* __restrict__ x_sel2, float* __restrict__ a2,
                          float* __restrict__ merged) {
  __shared__ int sidx[KS1]; __shared__ float stv[KS1];
  int g = blockIdx.x; int t = threadIdx.x;
  if (t < KS1) { sidx[t] = idx[g*KS1 + t]; stv[t] = tv[g*KS1 + t]; }
  __syncthreads();
  float sum = 0.f, mx = -INFINITY;
  for (int j = 0; j < KS1; ++j) {
    float v = x2[((size_t)g*KS0 + sidx[j])*DD + t] * stv[j];
    x_sel2[((size_t)g*KS1 + j)*DD + t] = v;
    sum += v; mx = fmaxf(mx, v);
  }
  merged[(size_t)g*1536 + 512 + t] = sum;
  merged[(size_t)g*1536 + 768 + t] = mx;
  {
    int r = t >> 4, c = t & 15;                   // 256 threads == 16x16
    a2[(size_t)g*KS1*KS1 + t] = a1[(size_t)g*KS0*KS0 + sidx[r]*KS0 + sidx[c]];
  }
}

__global__ void k_gather2(const float* __restrict__ x3, const int* __restrict__ idx,
                          const float* __restrict__ tv, float* __restrict__ merged) {
  __shared__ int sidx[KS2]; __shared__ float stv[KS2];
  int g = blockIdx.x; int t = threadIdx.x;
  if (t < KS2) { sidx[t] = idx[g*KS2 + t]; stv[t] = tv[g*KS2 + t]; }
  __syncthreads();
  float sum = 0.f, mx = -INFINITY;
  for (int j = 0; j < KS2; ++j) {
    float v = x3[((size_t)g*KS1 + sidx[j])*DD + t] * stv[j];
    sum += v; mx = fmaxf(mx, v);
  }
  merged[(size_t)g*1536 + 1024 + t] = sum;
  merged[(size_t)g*1536 + 1280 + t] = mx;
}

// ---------------- dense small spmm: norm from a, T = a @ (x*norm) ----------------
template<int n>
__global__ void k_spmm_dense(const float* __restrict__ a, const float* __restrict__ x,
                             float* __restrict__ normv, float* __restrict__ T) {
  __shared__ float sa[n*n];
  __shared__ float snorm[n];
  __shared__ float sx[n*DD];
  int g = blockIdx.x; int t = threadIdx.x;
  for (int e = t; e < n*n; e += 256) sa[e] = a[(size_t)g*n*n + e];
  __syncthreads();
  if (t < n) {
    float dg = 0.f;
    for (int m = 0; m < n; ++m) dg += sa[t*n + m];
    float nv = rsqrtf(fmaxf(dg, 1.f));
    snorm[t] = nv; normv[g*n + t] = nv;
  }
  __syncthreads();
  for (int e = t; e < n*DD; e += 256) sx[e] = x[(size_t)g*n*DD + e] * snorm[e >> 8];
  __syncthreads();
  float acc[n];
  #pragma unroll
  for (int r = 0; r < n; ++r) acc[r] = 0.f;
  for (int m = 0; m < n; ++m) {
    float xv = sx[m*DD + t];
    #pragma unroll
    for (int r = 0; r < n; ++r) acc[r] += sa[r*n + m]*xv;
  }
  for (int r = 0; r < n; ++r) T[((size_t)g*n + r)*DD + t] = acc[r];
}

// ---------------- final MLP ----------------
__global__ void k_mlp(const float* __restrict__ merged, const float* __restrict__ Wd1,
                      const float* __restrict__ bd1, const float* __restrict__ Wd2,
                      const float* __restrict__ bd2, float* __restrict__ out) {
  __shared__ float sm[1536];
  __shared__ float sh[128];
  int g = blockIdx.x; int t = threadIdx.x;     // 128 threads
  for (int i = t; i < 1536; i += 128) sm[i] = merged[(size_t)g*1536 + i];
  __syncthreads();
  float acc = 0.f;
  for (int k = 0; k < 1536; ++k) acc += sm[k]*Wd1[(size_t)k*128 + t];
  sh[t] = lrelu(acc + bd1[t]);
  __syncthreads();
  if (t < 2) {
    float o = 0.f;
    for (int k = 0; k < 128; ++k) o += sh[k]*Wd2[k*2 + t];
    out[(size_t)g*2 + t] = 1.f/(1.f + expf(-(o + bd2[t])));
  }
}

extern "C" void kernel_launch(void* const* d_in, const int* in_sizes, int n_in,
                              void* d_out, int out_size, void* d_ws, size_t ws_size,
                              hipStream_t stream) {
  const float* feat = (const float*)d_in[0];
  const float* adj  = (const float*)d_in[1];
  const float* W0 = (const float*)d_in[2];  const float* b0  = (const float*)d_in[3];
  const float* Ws0= (const float*)d_in[4];  const float* bs0 = (const float*)d_in[5];
  const float* W1 = (const float*)d_in[6];  const float* b1  = (const float*)d_in[7];
  const float* Ws1= (const float*)d_in[8];  const float* bs1 = (const float*)d_in[9];
  const float* W2 = (const float*)d_in[10]; const float* b2  = (const float*)d_in[11];
  const float* Ws2= (const float*)d_in[12]; const float* bs2 = (const float*)d_in[13];
  const float* Wd1= (const float*)d_in[14]; const float* bd1 = (const float*)d_in[15];
  const float* Wd2= (const float*)d_in[16]; const float* bd2 = (const float*)d_in[17];
  float* out = (float*)d_out;

  char* ws = (char*)d_ws;
  size_t off = 0;
  auto alloc = [&](size_t bytes) -> char* {
    char* p = ws + off; off += (bytes + 255) & ~(size_t)255; return p;
  };
  float* norm0 = (float*)alloc((size_t)GG*NN*4);
  int*   cnt0  = (int*)  alloc((size_t)GG*NN*4);
  unsigned char* nbr0 = (unsigned char*)alloc((size_t)GG*NN*MAXNB);
  float* hs0   = (float*)alloc((size_t)GG*NN*4);
  float* score0= (float*)alloc((size_t)GG*NN*4);
  int*   idx0  = (int*)  alloc((size_t)GG*KS0*4);
  float* tv0   = (float*)alloc((size_t)GG*KS0*4);
  float* norm1 = (float*)alloc((size_t)GG*KS0*4);
  float* hs1   = (float*)alloc((size_t)GG*KS0*4);
  float* score1= (float*)alloc((size_t)GG*KS0*4);
  int*   idx1  = (int*)  alloc((size_t)GG*KS1*4);
  float* tv1   = (float*)alloc((size_t)GG*KS1*4);
  float* norm2 = (float*)alloc((size_t)GG*KS1*4);
  float* hs2   = (float*)alloc((size_t)GG*KS1*4);
  float* score2= (float*)alloc((size_t)GG*KS1*4);
  int*   idx2  = (int*)  alloc((size_t)GG*KS2*4);
  float* tv2   = (float*)alloc((size_t)GG*KS2*4);
  float* merged= (float*)alloc((size_t)GG*1536*4);
  char* regA = alloc((size_t)GG*NN*FF*4);   // 128 MB
  char* regB = alloc((size_t)GG*NN*DD*4);   // 256 MB

  // region A: T0 first; after gemm0 done, reused for layer1+ buffers
  float* T0     = (float*)regA;
  float* x_sel1 = (float*)regA;                                        // 32 MB
  float* a1     = (float*)(regA + (size_t)GG*KS0*DD*4);                //  4 MB
  float* T1     = (float*)(regA + (size_t)(GG*KS0*DD + GG*KS0*KS0)*4); // 32 MB
  float* x2     = (float*)((char*)T1 + (size_t)GG*KS0*DD*4);           // 32 MB
  float* x_sel2 = (float*)((char*)x2 + (size_t)GG*KS0*DD*4);           // 16 MB
  float* a2     = (float*)((char*)x_sel2 + (size_t)GG*KS1*DD*4);       //  1 MB
  // region B: x1 first; after gather0 done, reused for layer2 buffers
  float* x1 = (float*)regB;
  float* T2 = (float*)regB;
  float* x3 = (float*)(regB + (size_t)GG*KS1*DD*4);

  // ---- layer 0 ----
  k_csr<<<GG, 256, 0, stream>>>(adj, norm0, cnt0, nbr0);
  k_spmm0<<<GG, 256, 0, stream>>>(feat, norm0, cnt0, nbr0, T0);
  { dim3 grid(GG*NN/128, DD/64); k_gemm<FF><<<grid, 256, 0, stream>>>(T0, W0, norm0, b0, x1); }
  k_hs<<<GG*NN/4, 256, 0, stream>>>(x1, Ws0, norm0, hs0);
  k_score0<<<GG, 256, 0, stream>>>(hs0, cnt0, nbr0, norm0, bs0, score0);
  k_topk<NN, KS0><<<GG/4, 256, 0, stream>>>(score0, idx0, tv0);
  k_gather0<<<GG, 256, 0, stream>>>(x1, adj, idx0, tv0, x_sel1, a1, merged);

  // ---- layer 1 ----
  k_spmm_dense<KS0><<<GG, 256, 0, stream>>>(a1, x_sel1, norm1, T1);
  { dim3 grid(GG*KS0/128, DD/64); k_gemm<DD><<<grid, 256, 0, stream>>>(T1, W1, norm1, b1, x2); }
  k_hs<<<GG*KS0/4, 256, 0, stream>>>(x2, Ws1, norm1, hs1);
  k_score_dense<KS0><<<(GG*KS0 + 255)/256, 256, 0, stream>>>(a1, hs1, norm1, bs1, score1);
  k_topk<KS0, KS1><<<GG/4, 256, 0, stream>>>(score1, idx1, tv1);
  k_gather1<<<GG, 256, 0, stream>>>(x2, a1, idx1, tv1, x_sel2, a2, merged);

  // ---- layer 2 ----
  k_spmm_dense<KS1><<<GG, 256, 0, stream>>>(a2, x_sel2, norm2, T2);
  { dim3 grid(GG*KS1/128, DD/64); k_gemm<DD><<<grid, 256, 0, stream>>>(T2, W2, norm2, b2, x3); }
  k_hs<<<GG*KS1/4, 256, 0, stream>>>(x3, Ws2, norm2, hs2);
  k_score_dense<KS1><<<(GG*KS1 + 255)/256, 256, 0, stream>>>(a2, hs2, norm2, bs2, score2);
  k_topk<KS1, KS2><<<GG/4, 256, 0, stream>>>(score2, idx2, tv2);
  k_gather2<<<GG, 256, 0, stream>>>(x3, idx2, tv2, merged);

  // ---- MLP head ----
  k_mlp<<<GG, 128, 0, stream>>>(merged, Wd1, bd1, Wd2, bd2, out);

  (void)in_sizes; (void)n_in; (void)out_size; (void)ws_size;
}

// Round 2
// 1310.559 us; speedup vs baseline: 1.3549x; 1.3549x over previous
//
#include <hip/hip_runtime.h>
#include <math.h>

constexpr int GG  = 1024;   // graphs
constexpr int NN  = 256;    // nodes layer0
constexpr int FF  = 128;    // input feat
constexpr int DD  = 256;    // hidden
constexpr int KS0 = 32, KS1 = 16, KS2 = 8;
constexpr int MAXNB = 96;   // max neighbors stored

__device__ __forceinline__ float lrelu(float x){ return x >= 0.f ? x : 0.01f*x; }

// bf16 helpers (manual, no __bf16 arithmetic needed)
__device__ __forceinline__ unsigned short f2bf(float f) {
  unsigned u = __float_as_uint(f);
  unsigned r = (u + 0x7FFFu + ((u >> 16) & 1u)) >> 16;
  return (unsigned short)r;
}
__device__ __forceinline__ float bf2f(unsigned short h) {
  return __uint_as_float(((unsigned)h) << 16);
}

typedef __attribute__((ext_vector_type(8)))  __bf16 bf16x8;
typedef __attribute__((ext_vector_type(16))) float  f32x16;

union U64pack { unsigned short us[4]; unsigned long long u; };
union Frag8   { unsigned short us[8]; unsigned long long u64[2]; bf16x8 v; };

// ---------------- CSR build + norm (layer 0) ----------------
__global__ void k_csr(const float* __restrict__ adj, float* __restrict__ norm0,
                      int* __restrict__ cnt0, unsigned char* __restrict__ nbr0) {
  int g = blockIdx.x;
  int lane = threadIdx.x & 63;
  int wave = threadIdx.x >> 6;
  const float* A = adj + (size_t)g*NN*NN;
  for (int r = wave*64; r < wave*64 + 64; ++r) {
    unsigned char* nb = nbr0 + ((size_t)g*NN + r)*MAXNB;
    int cnt = 0;
    for (int ch = 0; ch < 4; ++ch) {
      float v = A[(size_t)r*NN + ch*64 + lane];
      unsigned long long mask = __ballot(v > 0.5f);
      int pos = __popcll(mask & ((1ull << lane) - 1ull));
      if (v > 0.5f && cnt + pos < MAXNB) nb[cnt + pos] = (unsigned char)(ch*64 + lane);
      cnt += __popcll(mask);
    }
    if (lane == 0) {
      cnt0[g*NN + r] = cnt < MAXNB ? cnt : MAXNB;
      norm0[g*NN + r] = rsqrtf(fmaxf((float)cnt, 1.0f));
    }
  }
}

// ---------------- T0 = A @ (X*norm) via bf16 MFMA, 3-way split (exact since A binary) ----------------
__global__ __launch_bounds__(256) void k_spmm_mfma(
    const float* __restrict__ adj, const float* __restrict__ feat,
    const float* __restrict__ norm0, float* __restrict__ T0) {
  // X staged in LDS, k-major: xs[split][n(128)][k(32)+pad] bf16, row stride 36 bf16 = 72B
  __shared__ unsigned long long xs[3*128*9];       // 27648 B

  int g = blockIdx.x;
  int t = threadIdx.x;
  int lane = t & 63, wave = t >> 6;
  int lm = lane & 31, lh = lane >> 5;

  const float* Ag = adj  + (size_t)g*NN*NN;
  const float* Xg = feat + (size_t)g*NN*FF;
  const float* nv = norm0 + (size_t)g*NN;

  f32x16 acc[2][4];
  #pragma unroll
  for (int i = 0; i < 2; ++i)
    #pragma unroll
    for (int j = 0; j < 4; ++j) acc[i][j] = (f32x16)0.0f;

  int xn   = t & 127;          // column this thread stages
  int kg16 = (t >> 7) * 16;    // k-group (0 or 16)

  for (int kt = 0; kt < NN; kt += 32) {
    // ---- A fragment prefetch (global, rows owned exclusively by this wave) ----
    float4 af[2][2][2];   // [mt][s][16B half]
    #pragma unroll
    for (int mt = 0; mt < 2; ++mt)
      #pragma unroll
      for (int s = 0; s < 2; ++s) {
        const float* ap = Ag + (size_t)(wave*64 + mt*32 + lm)*NN + kt + s*16 + lh*8;
        af[mt][s][0] = *reinterpret_cast<const float4*>(ap);
        af[mt][s][1] = *reinterpret_cast<const float4*>(ap + 4);
      }

    // ---- X stage: load 16 k-rows for column xn, 3-way bf16 split, k-major LDS ----
    #pragma unroll
    for (int c = 0; c < 4; ++c) {
      U64pack p0, p1, p2;
      #pragma unroll
      for (int kk = 0; kk < 4; ++kk) {
        int m = kt + kg16 + c*4 + kk;
        float x = Xg[(size_t)m*FF + xn] * nv[m];
        unsigned short h1 = f2bf(x);  float r1 = x - bf2f(h1);
        unsigned short h2 = f2bf(r1); float r2 = r1 - bf2f(h2);
        unsigned short h3 = f2bf(r2);
        p0.us[kk] = h1; p1.us[kk] = h2; p2.us[kk] = h3;
      }
      int base = xn*9 + kg16/4 + c;
      xs[base        ] = p0.u;
      xs[base + 128*9] = p1.u;
      xs[base + 256*9] = p2.u;
    }
    __syncthreads();

    // ---- convert A frags ----
    Frag8 afr[2][2];
    #pragma unroll
    for (int mt = 0; mt < 2; ++mt)
      #pragma unroll
      for (int s = 0; s < 2; ++s) {
        const float* fv = &af[mt][s][0].x;
        #pragma unroll
        for (int j = 0; j < 8; ++j) afr[mt][s].us[j] = f2bf(fv[j]);
      }

    // ---- MFMA ----
    #pragma unroll
    for (int s = 0; s < 2; ++s)
      #pragma unroll
      for (int sp = 0; sp < 3; ++sp)
        #pragma unroll
        for (int nt = 0; nt < 4; ++nt) {
          int n = nt*32 + lm;
          int idx = (sp*128 + n)*9 + 4*s + 2*lh;
          Frag8 bf_;
          bf_.u64[0] = xs[idx];
          bf_.u64[1] = xs[idx + 1];
          #pragma unroll
          for (int mt = 0; mt < 2; ++mt)
            acc[mt][nt] = __builtin_amdgcn_mfma_f32_32x32x16_bf16(
                afr[mt][s].v, bf_.v, acc[mt][nt], 0, 0, 0);
        }
    __syncthreads();
  }

  // ---- epilogue: C/D layout col=lane&31, row=(reg&3)+8*(reg>>2)+4*(lane>>5) ----
  #pragma unroll
  for (int mt = 0; mt < 2; ++mt)
    #pragma unroll
    for (int nt = 0; nt < 4; ++nt)
      #pragma unroll
      for (int r = 0; r < 16; ++r) {
        int row = wave*64 + mt*32 + (r & 3) + 8*(r >> 2) + 4*lh;
        int col = nt*32 + lm;
        T0[((size_t)g*NN + row)*FF + col] = acc[mt][nt][r];
      }
}

// ---------------- dense GEMM: out = lrelu(norm[row]*(T@W) + bias), N=256 ----------------
template<int K>
__global__ __launch_bounds__(256) void k_gemm(const float* __restrict__ Tmat,
                       const float* __restrict__ W,
                       const float* __restrict__ normv, const float* __restrict__ bias,
                       float* __restrict__ out) {
  __shared__ float As[128*65];
  __shared__ float Bs[64*64];
  int m0 = blockIdx.x * 128;
  int n0 = blockIdx.y * 64;
  int t = threadIdx.x;
  int tx = t & 15, ty = t >> 4;
  float acc[8][4] = {};
  for (int kt = 0; kt < K; kt += 64) {
    __syncthreads();
    #pragma unroll
    for (int i = 0; i < 32; ++i) {
      int idx = t + i*256;                    // 128x64
      int r = idx >> 6, k = idx & 63;
      As[r*65 + k] = Tmat[(size_t)(m0 + r)*K + kt + k];
    }
    #pragma unroll
    for (int i = 0; i < 16; ++i) {
      int idx = t + i*256;                    // 64x64
      int k = idx >> 6, n = idx & 63;
      Bs[k*64 + n] = W[(size_t)(kt + k)*DD + n0 + n];
    }
    __syncthreads();
    for (int k = 0; k < 64; ++k) {
      float a[8];
      #pragma unroll
      for (int i = 0; i < 8; ++i) a[i] = As[(ty*8 + i)*65 + k];
      float4 b = *reinterpret_cast<const float4*>(&Bs[k*64 + tx*4]);
      #pragma unroll
      for (int i = 0; i < 8; ++i) {
        acc[i][0] += a[i]*b.x; acc[i][1] += a[i]*b.y;
        acc[i][2] += a[i]*b.z; acc[i][3] += a[i]*b.w;
      }
    }
  }
  #pragma unroll
  for (int i = 0; i < 8; ++i) {
    int row = m0 + ty*8 + i;
    float nv = normv[row];
    #pragma unroll
    for (int j = 0; j < 4; ++j) {
      int col = n0 + tx*4 + j;
      out[(size_t)row*DD + col] = lrelu(nv*acc[i][j] + bias[col]);
    }
  }
}

// ---------------- hs[row] = norm[row] * dot(X[row,:256], Ws) ----------------
__global__ void k_hs(const float* __restrict__ X, const float* __restrict__ Ws,
                     const float* __restrict__ normv, float* __restrict__ hs) {
  int row = blockIdx.x*4 + (threadIdx.x >> 6);
  int lane = threadIdx.x & 63;
  const float* x = X + (size_t)row*DD;
  float s = x[lane]*Ws[lane] + x[lane+64]*Ws[lane+64]
          + x[lane+128]*Ws[lane+128] + x[lane+192]*Ws[lane+192];
  for (int off = 32; off; off >>= 1) s += __shfl_xor(s, off);
  if (lane == 0) hs[row] = normv[row]*s;
}

// ---------------- score layer0 (sparse) ----------------
__global__ void k_score0(const float* __restrict__ hs, const int* __restrict__ cnt0,
                         const unsigned char* __restrict__ nbr0, const float* __restrict__ norm0,
                         const float* __restrict__ bs, float* __restrict__ score) {
  int g = blockIdx.x; int r = threadIdx.x;
  int cnt = cnt0[g*NN + r];
  const unsigned char* nb = nbr0 + ((size_t)g*NN + r)*MAXNB;
  float s = 0.f;
  for (int j = 0; j < cnt; ++j) s += hs[g*NN + nb[j]];
  score[g*NN + r] = norm0[g*NN + r]*s + bs[0];
}

// ---------------- score layers 1/2 (dense small) ----------------
template<int n>
__global__ void k_score_dense(const float* __restrict__ a, const float* __restrict__ hs,
                              const float* __restrict__ normv, const float* __restrict__ bs,
                              float* __restrict__ score) {
  int row = blockIdx.x*blockDim.x + threadIdx.x;   // over GG*n
  if (row >= GG*n) return;
  int g = row / n;
  const float* ar = a + (size_t)g*n*n + (size_t)(row - g*n)*n;
  float s = 0.f;
  for (int m = 0; m < n; ++m) s += ar[m]*hs[g*n + m];
  score[row] = normv[row]*s + bs[0];
}

// ---------------- top-k per graph (one wave per graph), ties -> lower index ----------------
template<int n, int k>
__global__ void k_topk(const float* __restrict__ score, int* __restrict__ idx_out,
                       float* __restrict__ tv_out) {
  int g = blockIdx.x*4 + (threadIdx.x >> 6);
  int lane = threadIdx.x & 63;
  constexpr int E = (n + 63)/64;
  float s[E]; int si[E];
  #pragma unroll
  for (int e = 0; e < E; ++e) {
    int i = e*64 + lane;
    if (i < n) { s[e] = score[(size_t)g*n + i]; si[e] = i; }
    else { s[e] = -INFINITY; si[e] = 1 << 30; }
  }
  for (int kk = 0; kk < k; ++kk) {
    float bs_ = -INFINITY; int bi = 1 << 30;
    #pragma unroll
    for (int e = 0; e < E; ++e)
      if (s[e] > bs_ || (s[e] == bs_ && si[e] < bi)) { bs_ = s[e]; bi = si[e]; }
    for (int off = 32; off; off >>= 1) {
      float os = __shfl_xor(bs_, off);
      int oi = __shfl_xor(bi, off);
      if (os > bs_ || (os == bs_ && oi < bi)) { bs_ = os; bi = oi; }
    }
    if (lane == 0) { idx_out[(size_t)g*k + kk] = bi; tv_out[(size_t)g*k + kk] = tanhf(bs_); }
    #pragma unroll
    for (int e = 0; e < E; ++e) if (si[e] == bi) s[e] = -INFINITY;
  }
}

// ---------------- gathers + readouts ----------------
__global__ void k_gather0(const float* __restrict__ x1, const float* __restrict__ adj,
                          const int* __restrict__ idx, const float* __restrict__ tv,
                          float* __restrict__ x_sel, float* __restrict__ a1,
                          float* __restrict__ merged) {
  __shared__ int sidx[KS0]; __shared__ float stv[KS0];
  int g = blockIdx.x; int t = threadIdx.x;
  if (t < KS0) { sidx[t] = idx[g*KS0 + t]; stv[t] = tv[g*KS0 + t]; }
  __syncthreads();
  float sum = 0.f, mx = -INFINITY;
  for (int j = 0; j < KS0; ++j) {
    float v = x1[((size_t)g*NN + sidx[j])*DD + t] * stv[j];
    x_sel[((size_t)g*KS0 + j)*DD + t] = v;
    sum += v; mx = fmaxf(mx, v);
  }
  merged[(size_t)g*1536 + t] = sum;
  merged[(size_t)g*1536 + 256 + t] = mx;
  for (int e = t; e < KS0*KS0; e += 256) {
    int r = e >> 5, c = e & 31;
    a1[(size_t)g*KS0*KS0 + e] = adj[(size_t)g*NN*NN + (size_t)sidx[r]*NN + sidx[c]];
  }
}

__global__ void k_gather1(const float* __restrict__ x2, const float* __restrict__ a1,
                          const int* __restrict__ idx, const float* __restrict__ tv,
                          float* __restrict__ x_sel2, float* __restrict__ a2,
                          float* __restrict__ merged) {
  __shared__ int sidx[KS1]; __shared__ float stv[KS1];
  int g = blockIdx.x; int t = threadIdx.x;
  if (t < KS1) { sidx[t] = idx[g*KS1 + t]; stv[t] = tv[g*KS1 + t]; }
  __syncthreads();
  float sum = 0.f, mx = -INFINITY;
  for (int j = 0; j < KS1; ++j) {
    float v = x2[((size_t)g*KS0 + sidx[j])*DD + t] * stv[j];
    x_sel2[((size_t)g*KS1 + j)*DD + t] = v;
    sum += v; mx = fmaxf(mx, v);
  }
  merged[(size_t)g*1536 + 512 + t] = sum;
  merged[(size_t)g*1536 + 768 + t] = mx;
  {
    int r = t >> 4, c = t & 15;                   // 256 threads == 16x16
    a2[(size_t)g*KS1*KS1 + t] = a1[(size_t)g*KS0*KS0 + sidx[r]*KS0 + sidx[c]];
  }
}

__global__ void k_gather2(const float* __restrict__ x3, const int* __restrict__ idx,
                          const float* __restrict__ tv, float* __restrict__ merged) {
  __shared__ int sidx[KS2]; __shared__ float stv[KS2];
  int g = blockIdx.x; int t = threadIdx.x;
  if (t < KS2) { sidx[t] = idx[g*KS2 + t]; stv[t] = tv[g*KS2 + t]; }
  __syncthreads();
  float sum = 0.f, mx = -INFINITY;
  for (int j = 0; j < KS2; ++j) {
    float v = x3[((size_t)g*KS1 + sidx[j])*DD + t] * stv[j];
    sum += v; mx = fmaxf(mx, v);
  }
  merged[(size_t)g*1536 + 1024 + t] = sum;
  merged[(size_t)g*1536 + 1280 + t] = mx;
}

// ---------------- dense small spmm: norm from a, T = a @ (x*norm) ----------------
template<int n>
__global__ void k_spmm_dense(const float* __restrict__ a, const float* __restrict__ x,
                             float* __restrict__ normv, float* __restrict__ T) {
  __shared__ float sa[n*n];
  __shared__ float snorm[n];
  __shared__ float sx[n*DD];
  int g = blockIdx.x; int t = threadIdx.x;
  for (int e = t; e < n*n; e += 256) sa[e] = a[(size_t)g*n*n + e];
  __syncthreads();
  if (t < n) {
    float dg = 0.f;
    for (int m = 0; m < n; ++m) dg += sa[t*n + m];
    float nv = rsqrtf(fmaxf(dg, 1.f));
    snorm[t] = nv; normv[g*n + t] = nv;
  }
  __syncthreads();
  for (int e = t; e < n*DD; e += 256) sx[e] = x[(size_t)g*n*DD + e] * snorm[e >> 8];
  __syncthreads();
  float acc[n];
  #pragma unroll
  for (int r = 0; r < n; ++r) acc[r] = 0.f;
  for (int m = 0; m < n; ++m) {
    float xv = sx[m*DD + t];
    #pragma unroll
    for (int r = 0; r < n; ++r) acc[r] += sa[r*n + m]*xv;
  }
  for (int r = 0; r < n; ++r) T[((size_t)g*n + r)*DD + t] = acc[r];
}

// ---------------- final MLP ----------------
__global__ void k_mlp(const float* __restrict__ merged, const float* __restrict__ Wd1,
                      const float* __restrict__ bd1, const float* __restrict__ Wd2,
                      const float* __restrict__ bd2, float* __restrict__ out) {
  __shared__ float sm[1536];
  __shared__ float sh[128];
  int g = blockIdx.x; int t = threadIdx.x;     // 128 threads
  for (int i = t; i < 1536; i += 128) sm[i] = merged[(size_t)g*1536 + i];
  __syncthreads();
  float acc = 0.f;
  for (int k = 0; k < 1536; ++k) acc += sm[k]*Wd1[(size_t)k*128 + t];
  sh[t] = lrelu(acc + bd1[t]);
  __syncthreads();
  if (t < 2) {
    float o = 0.f;
    for (int k = 0; k < 128; ++k) o += sh[k]*Wd2[k*2 + t];
    out[(size_t)g*2 + t] = 1.f/(1.f + expf(-(o + bd2[t])));
  }
}

extern "C" void kernel_launch(void* const* d_in, const int* in_sizes, int n_in,
                              void* d_out, int out_size, void* d_ws, size_t ws_size,
                              hipStream_t stream) {
  const float* feat = (const float*)d_in[0];
  const float* adj  = (const float*)d_in[1];
  const float* W0 = (const float*)d_in[2];  const float* b0  = (const float*)d_in[3];
  const float* Ws0= (const float*)d_in[4];  const float* bs0 = (const float*)d_in[5];
  const float* W1 = (const float*)d_in[6];  const float* b1  = (const float*)d_in[7];
  const float* Ws1= (const float*)d_in[8];  const float* bs1 = (const float*)d_in[9];
  const float* W2 = (const float*)d_in[10]; const float* b2  = (const float*)d_in[11];
  const float* Ws2= (const float*)d_in[12]; const float* bs2 = (const float*)d_in[13];
  const float* Wd1= (const float*)d_in[14]; const float* bd1 = (const float*)d_in[15];
  const float* Wd2= (const float*)d_in[16]; const float* bd2 = (const float*)d_in[17];
  float* out = (float*)d_out;

  char* ws = (char*)d_ws;
  size_t off = 0;
  auto alloc = [&](size_t bytes) -> char* {
    char* p = ws + off; off += (bytes + 255) & ~(size_t)255; return p;
  };
  float* norm0 = (float*)alloc((size_t)GG*NN*4);
  int*   cnt0  = (int*)  alloc((size_t)GG*NN*4);
  unsigned char* nbr0 = (unsigned char*)alloc((size_t)GG*NN*MAXNB);
  float* hs0   = (float*)alloc((size_t)GG*NN*4);
  float* score0= (float*)alloc((size_t)GG*NN*4);
  int*   idx0  = (int*)  alloc((size_t)GG*KS0*4);
  float* tv0   = (float*)alloc((size_t)GG*KS0*4);
  float* norm1 = (float*)alloc((size_t)GG*KS0*4);
  float* hs1   = (float*)alloc((size_t)GG*KS0*4);
  float* score1= (float*)alloc((size_t)GG*KS0*4);
  int*   idx1  = (int*)  alloc((size_t)GG*KS1*4);
  float* tv1   = (float*)alloc((size_t)GG*KS1*4);
  float* norm2 = (float*)alloc((size_t)GG*KS1*4);
  float* hs2   = (float*)alloc((size_t)GG*KS1*4);
  float* score2= (float*)alloc((size_t)GG*KS1*4);
  int*   idx2  = (int*)  alloc((size_t)GG*KS2*4);
  float* tv2   = (float*)alloc((size_t)GG*KS2*4);
  float* merged= (float*)alloc((size_t)GG*1536*4);
  char* regA = alloc((size_t)GG*NN*FF*4);   // 128 MB
  char* regB = alloc((size_t)GG*NN*DD*4);   // 256 MB

  // region A: T0 first; after gemm0 done, reused for layer1+ buffers
  float* T0     = (float*)regA;
  float* x_sel1 = (float*)regA;                                        // 32 MB
  float* a1     = (float*)(regA + (size_t)GG*KS0*DD*4);                //  4 MB
  float* T1     = (float*)(regA + (size_t)(GG*KS0*DD + GG*KS0*KS0)*4); // 32 MB
  float* x2     = (float*)((char*)T1 + (size_t)GG*KS0*DD*4);           // 32 MB
  float* x_sel2 = (float*)((char*)x2 + (size_t)GG*KS0*DD*4);           // 16 MB
  float* a2     = (float*)((char*)x_sel2 + (size_t)GG*KS1*DD*4);       //  1 MB
  // region B: x1 first; after gather0 done, reused for layer2 buffers
  float* x1 = (float*)regB;
  float* T2 = (float*)regB;
  float* x3 = (float*)(regB + (size_t)GG*KS1*DD*4);

  // ---- layer 0 ----
  k_csr<<<GG, 256, 0, stream>>>(adj, norm0, cnt0, nbr0);
  k_spmm_mfma<<<GG, 256, 0, stream>>>(adj, feat, norm0, T0);
  { dim3 grid(GG*NN/128, DD/64); k_gemm<FF><<<grid, 256, 0, stream>>>(T0, W0, norm0, b0, x1); }
  k_hs<<<GG*NN/4, 256, 0, stream>>>(x1, Ws0, norm0, hs0);
  k_score0<<<GG, 256, 0, stream>>>(hs0, cnt0, nbr0, norm0, bs0, score0);
  k_topk<NN, KS0><<<GG/4, 256, 0, stream>>>(score0, idx0, tv0);
  k_gather0<<<GG, 256, 0, stream>>>(x1, adj, idx0, tv0, x_sel1, a1, merged);

  // ---- layer 1 ----
  k_spmm_dense<KS0><<<GG, 256, 0, stream>>>(a1, x_sel1, norm1, T1);
  { dim3 grid(GG*KS0/128, DD/64); k_gemm<DD><<<grid, 256, 0, stream>>>(T1, W1, norm1, b1, x2); }
  k_hs<<<GG*KS0/4, 256, 0, stream>>>(x2, Ws1, norm1, hs1);
  k_score_dense<KS0><<<(GG*KS0 + 255)/256, 256, 0, stream>>>(a1, hs1, norm1, bs1, score1);
  k_topk<KS0, KS1><<<GG/4, 256, 0, stream>>>(score1, idx1, tv1);
  k_gather1<<<GG, 256, 0, stream>>>(x2, a1, idx1, tv1, x_sel2, a2, merged);

  // ---- layer 2 ----
  k_spmm_dense<KS1><<<GG, 256, 0, stream>>>(a2, x_sel2, norm2, T2);
  { dim3 grid(GG*KS1/128, DD/64); k_gemm<DD><<<grid, 256, 0, stream>>>(T2, W2, norm2, b2, x3); }
  k_hs<<<GG*KS1/4, 256, 0, stream>>>(x3, Ws2, norm2, hs2);
  k_score_dense<KS1><<<(GG*KS1 + 255)/256, 256, 0, stream>>>(a2, hs2, norm2, bs2, score2);
  k_topk<KS1, KS2><<<GG/4, 256, 0, stream>>>(score2, idx2, tv2);
  k_gather2<<<GG, 256, 0, stream>>>(x3, idx2, tv2, merged);

  // ---- MLP head ----
  k_mlp<<<GG, 128, 0, stream>>>(merged, Wd1, bd1, Wd2, bd2, out);

  (void)in_sizes; (void)n_in; (void)out_size; (void)ws_size;
}